// Round 1
// baseline (3363.774 us; speedup 1.0000x reference)
//
#include <hip/hip_runtime.h>
#include <hip/hip_bf16.h>
#include <hip/amd_detail/amd_hip_unsafe_atomics.h>

#define IN_DIM 256
#define OUT_DIM 256
#define NHEADS 4
#define NEG_SLOPE 0.2f

__device__ __forceinline__ float bf2f(unsigned short v) {
    return __uint_as_float(((unsigned int)v) << 16);
}
__device__ __forceinline__ unsigned short f2bf(float f) {
    unsigned int b = __float_as_uint(f);
    b += 0x7FFFu + ((b >> 16) & 1u);   // RNE
    return (unsigned short)(b >> 16);
}
__device__ __forceinline__ float lrelu(float v) { return v > 0.f ? v : NEG_SLOPE * v; }

// order-preserving float<->uint for atomicMax
__device__ __forceinline__ unsigned int f2sort(float f) {
    unsigned int b = __float_as_uint(f);
    return (b & 0x80000000u) ? ~b : (b | 0x80000000u);
}
__device__ __forceinline__ float sort2f(unsigned int u) {
    return __uint_as_float((u & 0x80000000u) ? (u & 0x7FFFFFFFu) : ~u);
}

__device__ __forceinline__ void eread(const void* e, int is64, int i, int E, int& s, int& d) {
    if (is64) {
        const long long* p = (const long long*)e;
        s = (int)p[i]; d = (int)p[(size_t)E + i];
    } else {
        const int* p = (const int*)e;
        s = p[i]; d = p[(size_t)E + i];
    }
}

// ---------- dtype detection: flags[0]=x is bf16, flags[1]=edge_index is int64 ----------
__global__ void k_detect(const void* x, const void* eidx, int* flags) {
    int t = threadIdx.x;  // 64 threads
    // float detection: sample even uint16s. If fp32, these are low mantissa halves
    // (random bits -> wild bf16 exponents). If bf16, they are N(0,1) values.
    const unsigned short* u = (const unsigned short*)x;
    unsigned short v = u[2 * t];
    int e = (v >> 7) & 0xFF;
    int sane = (e >= 118 && e <= 137) || ((v & 0x7FFFu) == 0);
    unsigned long long mf = __ballot(sane);
    // int detection: odd int32 slots. If int64 (values < 2^31), all high words are 0.
    const int* ip = (const int*)eidx;
    unsigned long long mi = __ballot(ip[2 * t + 1] == 0);
    if (t == 0) {
        flags[0] = (__popcll(mf) >= 48) ? 1 : 0;
        flags[1] = (mi == ~0ull) ? 1 : 0;
    }
}

// ---------- convert W / att vectors to fp32 scratch ----------
__global__ void k_convert(const void* W, const void* as, const void* ad,
                          float* Wf, float* asf, float* adf, const int* flags) {
    int i = blockIdx.x * 256 + threadIdx.x;
    int isb = flags[0];
    if (i < IN_DIM * OUT_DIM) {
        Wf[i] = isb ? bf2f(((const unsigned short*)W)[i]) : ((const float*)W)[i];
    } else if (i < IN_DIM * OUT_DIM + 256) {
        int j = i - IN_DIM * OUT_DIM;
        asf[j] = isb ? bf2f(((const unsigned short*)as)[j]) : ((const float*)as)[j];
    } else if (i < IN_DIM * OUT_DIM + 512) {
        int j = i - IN_DIM * OUT_DIM - 256;
        adf[j] = isb ? bf2f(((const unsigned short*)ad)[j]) : ((const float*)ad)[j];
    }
}

// ---------- xp = x @ W : 16 rows per block, thread t = output column ----------
__global__ __launch_bounds__(256) void k_gemm(const void* x, const float* __restrict__ Wf,
                                              float* __restrict__ xp, const int* flags, int n) {
    __shared__ float xs[16][IN_DIM];
    int t = threadIdx.x;
    int row0 = blockIdx.x * 16;
    int rows = n - row0; if (rows > 16) rows = 16;
    if (flags[0]) {
        const unsigned short* xb = (const unsigned short*)x;
        for (int j = 0; j < rows; ++j) xs[j][t] = bf2f(xb[(size_t)(row0 + j) * IN_DIM + t]);
    } else {
        const float* xf = (const float*)x;
        for (int j = 0; j < rows; ++j) xs[j][t] = xf[(size_t)(row0 + j) * IN_DIM + t];
    }
    __syncthreads();
    float a[16];
#pragma unroll
    for (int r = 0; r < 16; ++r) a[r] = 0.f;
    for (int k = 0; k < IN_DIM; ++k) {
        float wv = Wf[(size_t)k * OUT_DIM + t];
#pragma unroll
        for (int r = 0; r < 16; ++r) a[r] += xs[r][k] * wv;  // xs broadcast read: conflict-free
    }
    for (int r = 0; r < rows; ++r) xp[(size_t)(row0 + r) * OUT_DIM + t] = a[r];
}

// ---------- a_src/a_dst: one wave per node ----------
__global__ __launch_bounds__(256) void k_attdot(const float* __restrict__ xp,
                                                const float* __restrict__ asf,
                                                const float* __restrict__ adf,
                                                float* a_src, float* a_dst, int n) {
    int wave = (blockIdx.x * 256 + threadIdx.x) >> 6;
    int lane = threadIdx.x & 63;
    if (wave >= n) return;
    float4 v = ((const float4*)(xp + (size_t)wave * OUT_DIM))[lane];
    float4 s4 = ((const float4*)asf)[lane];
    float4 d4 = ((const float4*)adf)[lane];
    float ps = v.x * s4.x + v.y * s4.y + v.z * s4.z + v.w * s4.w;
    float pd = v.x * d4.x + v.y * d4.y + v.z * d4.z + v.w * d4.w;
#pragma unroll
    for (int m = 1; m < 16; m <<= 1) { ps += __shfl_xor(ps, m); pd += __shfl_xor(pd, m); }
    if ((lane & 15) == 0) {
        int h = lane >> 4;
        a_src[wave * NHEADS + h] = ps;
        a_dst[wave * NHEADS + h] = pd;
    }
}

// ---------- pass 1 over edges: segment max ----------
__global__ __launch_bounds__(256) void k_emax(const void* eidx, const float* __restrict__ a_src,
                                              const float* __restrict__ a_dst,
                                              unsigned int* emax, const int* flags, int E, int n) {
    int i = blockIdx.x * 256 + threadIdx.x;
    if (i >= E + n) return;
    int s, d;
    if (i < E) eread(eidx, flags[1], i, E, s, d); else { s = i - E; d = s; }
#pragma unroll
    for (int h = 0; h < NHEADS; ++h) {
        float v = lrelu(a_src[s * NHEADS + h] + a_dst[d * NHEADS + h]);
        atomicMax(&emax[d * NHEADS + h], f2sort(v));
    }
}

// ---------- pass 2 over edges: denom += w ; acc[dst] += w * xp[src] (one wave/edge) ----------
__global__ __launch_bounds__(256) void k_eagg(const void* eidx, const float* __restrict__ a_src,
                                              const float* __restrict__ a_dst,
                                              const unsigned int* __restrict__ emax,
                                              const float* __restrict__ xp,
                                              float* denom, float* acc,
                                              const int* flags, int E, int n) {
    int wid = (blockIdx.x * 256 + threadIdx.x) >> 6;
    int lane = threadIdx.x & 63;
    if (wid >= E + n) return;
    int s, d;
    if (wid < E) eread(eidx, flags[1], wid, E, s, d); else { s = wid - E; d = s; }
    int h = lane >> 4;
    float v = lrelu(a_src[s * NHEADS + h] + a_dst[d * NHEADS + h]);
    float m = sort2f(emax[d * NHEADS + h]);
    float w = __expf(v - m);
    if ((lane & 15) == 0) unsafeAtomicAdd(&denom[d * NHEADS + h], w);
    float4 xv = ((const float4*)(xp + (size_t)s * OUT_DIM))[lane];
    float* ap = acc + (size_t)d * OUT_DIM + lane * 4;
    unsafeAtomicAdd(ap + 0, w * xv.x);
    unsafeAtomicAdd(ap + 1, w * xv.y);
    unsafeAtomicAdd(ap + 2, w * xv.z);
    unsafeAtomicAdd(ap + 3, w * xv.w);
}

// ---------- finalize: out = relu(acc / denom), dtype per flag ----------
__global__ __launch_bounds__(256) void k_final(const float* __restrict__ acc,
                                               const float* __restrict__ denom,
                                               void* out, const int* flags, int n) {
    int i = blockIdx.x * 256 + threadIdx.x;
    if (i >= n * OUT_DIM) return;
    int node = i >> 8;
    int h = (i & 255) >> 6;
    float o = acc[i] / denom[node * NHEADS + h];
    o = o > 0.f ? o : 0.f;
    if (flags[0]) ((unsigned short*)out)[i] = f2bf(o);
    else          ((float*)out)[i] = o;
}

extern "C" void kernel_launch(void* const* d_in, const int* in_sizes, int n_in,
                              void* d_out, int out_size, void* d_ws, size_t ws_size,
                              hipStream_t stream) {
    const void* x    = d_in[0];
    const void* eidx = d_in[1];
    const void* W    = d_in[2];
    const void* as   = d_in[3];
    const void* ad   = d_in[4];
    int n = in_sizes[0] / IN_DIM;   // 50000
    int E = in_sizes[1] / 2;        // 800000

    char* ws = (char*)d_ws;
    size_t off = 0;
    auto alloc = [&](size_t bytes) -> void* {
        void* p = ws + off;
        off += (bytes + 255) & ~(size_t)255;
        return p;
    };
    int*          flags = (int*)alloc(16);
    float*        Wf    = (float*)alloc((size_t)IN_DIM * OUT_DIM * 4);
    float*        asf   = (float*)alloc(256 * 4);
    float*        adf   = (float*)alloc(256 * 4);
    float*        xp    = (float*)alloc((size_t)n * OUT_DIM * 4);
    float*        a_src = (float*)alloc((size_t)n * NHEADS * 4);
    float*        a_dst = (float*)alloc((size_t)n * NHEADS * 4);
    // contiguous zero-init region: emax | denom | acc
    unsigned int* emax  = (unsigned int*)alloc((size_t)n * NHEADS * 4);
    float*        denom = (float*)alloc((size_t)n * NHEADS * 4);
    float*        acc   = (float*)alloc((size_t)n * OUT_DIM * 4);
    size_t zbytes = (size_t)((char*)(acc + (size_t)n * OUT_DIM) - (char*)emax);
    hipMemsetAsync(emax, 0, zbytes, stream);  // 0 == sortable(-inf-ish) identity; denom/acc zeros

    hipLaunchKernelGGL(k_detect, dim3(1), dim3(64), 0, stream, x, eidx, flags);
    hipLaunchKernelGGL(k_convert, dim3((IN_DIM * OUT_DIM + 512 + 255) / 256), dim3(256), 0, stream,
                       W, as, ad, Wf, asf, adf, flags);
    hipLaunchKernelGGL(k_gemm, dim3((n + 15) / 16), dim3(256), 0, stream, x, Wf, xp, flags, n);
    hipLaunchKernelGGL(k_attdot, dim3((n + 3) / 4), dim3(256), 0, stream, xp, asf, adf, a_src, a_dst, n);
    int EN = E + n;
    hipLaunchKernelGGL(k_emax, dim3((EN + 255) / 256), dim3(256), 0, stream,
                       eidx, a_src, a_dst, emax, flags, E, n);
    hipLaunchKernelGGL(k_eagg, dim3((EN + 3) / 4), dim3(256), 0, stream,
                       eidx, a_src, a_dst, emax, xp, denom, acc, flags, E, n);
    hipLaunchKernelGGL(k_final, dim3((n * OUT_DIM + 255) / 256), dim3(256), 0, stream,
                       acc, denom, d_out, flags, n);
}

// Round 2
// 757.056 us; speedup vs baseline: 4.4432x; 4.4432x over previous
//
#include <hip/hip_runtime.h>
#include <hip/hip_bf16.h>

#define IN_DIM 256
#define OUT_DIM 256
#define NHEADS 4
#define NEG_SLOPE 0.2f

__device__ __forceinline__ float bf2f(unsigned short v) {
    return __uint_as_float(((unsigned int)v) << 16);
}
__device__ __forceinline__ unsigned short f2bf(float f) {
    unsigned int b = __float_as_uint(f);
    b += 0x7FFFu + ((b >> 16) & 1u);   // RNE
    return (unsigned short)(b >> 16);
}
__device__ __forceinline__ float lrelu(float v) { return v > 0.f ? v : NEG_SLOPE * v; }

__device__ __forceinline__ void eread(const void* e, int is64, int i, int E, int& s, int& d) {
    if (is64) {
        const long long* p = (const long long*)e;
        s = (int)p[i]; d = (int)p[(size_t)E + i];
    } else {
        const int* p = (const int*)e;
        s = p[i]; d = p[(size_t)E + i];
    }
}

// ---------- dtype detection: flags[0]=x is bf16, flags[1]=edge_index is int64 ----------
__global__ void k_detect(const void* x, const void* eidx, int* flags) {
    int t = threadIdx.x;  // 64 threads
    const unsigned short* u = (const unsigned short*)x;
    unsigned short v = u[2 * t];
    int e = (v >> 7) & 0xFF;
    int sane = (e >= 118 && e <= 137) || ((v & 0x7FFFu) == 0);
    unsigned long long mf = __ballot(sane);
    const int* ip = (const int*)eidx;
    unsigned long long mi = __ballot(ip[2 * t + 1] == 0);
    if (t == 0) {
        flags[0] = (__popcll(mf) >= 48) ? 1 : 0;
        flags[1] = (mi == ~0ull) ? 1 : 0;
    }
}

// ---------- convert W / att vectors to fp32 scratch ----------
__global__ void k_convert(const void* W, const void* as, const void* ad,
                          float* Wf, float* asf, float* adf, const int* flags) {
    int i = blockIdx.x * 256 + threadIdx.x;
    int isb = flags[0];
    if (i < IN_DIM * OUT_DIM) {
        Wf[i] = isb ? bf2f(((const unsigned short*)W)[i]) : ((const float*)W)[i];
    } else if (i < IN_DIM * OUT_DIM + 256) {
        int j = i - IN_DIM * OUT_DIM;
        asf[j] = isb ? bf2f(((const unsigned short*)as)[j]) : ((const float*)as)[j];
    } else if (i < IN_DIM * OUT_DIM + 512) {
        int j = i - IN_DIM * OUT_DIM - 256;
        adf[j] = isb ? bf2f(((const unsigned short*)ad)[j]) : ((const float*)ad)[j];
    }
}

// ---------- xp = x @ W : 16 rows per block, thread t = output column ----------
__global__ __launch_bounds__(256) void k_gemm(const void* x, const float* __restrict__ Wf,
                                              float* __restrict__ xp, const int* flags, int n) {
    __shared__ float xs[16][IN_DIM];
    int t = threadIdx.x;
    int row0 = blockIdx.x * 16;
    int rows = n - row0; if (rows > 16) rows = 16;
    if (flags[0]) {
        const unsigned short* xb = (const unsigned short*)x;
        for (int j = 0; j < rows; ++j) xs[j][t] = bf2f(xb[(size_t)(row0 + j) * IN_DIM + t]);
    } else {
        const float* xf = (const float*)x;
        for (int j = 0; j < rows; ++j) xs[j][t] = xf[(size_t)(row0 + j) * IN_DIM + t];
    }
    __syncthreads();
    float a[16];
#pragma unroll
    for (int r = 0; r < 16; ++r) a[r] = 0.f;
    for (int k = 0; k < IN_DIM; ++k) {
        float wv = Wf[(size_t)k * OUT_DIM + t];
#pragma unroll
        for (int r = 0; r < 16; ++r) a[r] += xs[r][k] * wv;
    }
    for (int r = 0; r < rows; ++r) xp[(size_t)(row0 + r) * OUT_DIM + t] = a[r];
}

// ---------- a_src/a_dst: one wave per node ----------
__global__ __launch_bounds__(256) void k_attdot(const float* __restrict__ xp,
                                                const float* __restrict__ asf,
                                                const float* __restrict__ adf,
                                                float* a_src, float* a_dst, int n) {
    int wave = (blockIdx.x * 256 + threadIdx.x) >> 6;
    int lane = threadIdx.x & 63;
    if (wave >= n) return;
    float4 v = ((const float4*)(xp + (size_t)wave * OUT_DIM))[lane];
    float4 s4 = ((const float4*)asf)[lane];
    float4 d4 = ((const float4*)adf)[lane];
    float ps = v.x * s4.x + v.y * s4.y + v.z * s4.z + v.w * s4.w;
    float pd = v.x * d4.x + v.y * d4.y + v.z * d4.z + v.w * d4.w;
#pragma unroll
    for (int m = 1; m < 16; m <<= 1) { ps += __shfl_xor(ps, m); pd += __shfl_xor(pd, m); }
    if ((lane & 15) == 0) {
        int h = lane >> 4;
        a_src[wave * NHEADS + h] = ps;
        a_dst[wave * NHEADS + h] = pd;
    }
}

// ---------- CSR build: in-degree histogram ----------
__global__ __launch_bounds__(256) void k_hist(const void* eidx, int* cnt,
                                              const int* flags, int E) {
    int i = blockIdx.x * 256 + threadIdx.x;
    if (i >= E) return;
    int s, d;
    eread(eidx, flags[1], i, E, s, d);
    atomicAdd(&cnt[d], 1);
}

// ---------- single-block exclusive scan over n counts -> off[n+1], cursor copy ----------
__global__ __launch_bounds__(256) void k_scan(const int* __restrict__ cnt,
                                              int* off, int* cursor, int n) {
    __shared__ int tmp[256];
    __shared__ int base;
    if (threadIdx.x == 0) base = 0;
    __syncthreads();
    for (int c0 = 0; c0 < n; c0 += 256) {
        int i = c0 + threadIdx.x;
        int v = (i < n) ? cnt[i] : 0;
        tmp[threadIdx.x] = v;
        __syncthreads();
        for (int s = 1; s < 256; s <<= 1) {
            int t = (threadIdx.x >= s) ? tmp[threadIdx.x - s] : 0;
            __syncthreads();
            tmp[threadIdx.x] += t;
            __syncthreads();
        }
        int excl = base + tmp[threadIdx.x] - v;
        if (i < n) { off[i] = excl; cursor[i] = excl; }
        __syncthreads();
        if (threadIdx.x == 255) base += tmp[255];
        __syncthreads();
    }
    if (threadIdx.x == 0) off[n] = base;
}

// ---------- scatter src indices into CSR buckets ----------
__global__ __launch_bounds__(256) void k_scatter(const void* eidx, int* cursor, int* csr,
                                                 const int* flags, int E) {
    int i = blockIdx.x * 256 + threadIdx.x;
    if (i >= E) return;
    int s, d;
    eread(eidx, flags[1], i, E, s, d);
    int pos = atomicAdd(&cursor[d], 1);
    csr[pos] = s;
}

// ---------- wave-per-dst aggregation: max, softmax-weighted gather, relu, store ----------
__global__ __launch_bounds__(256) void k_agg(const int* __restrict__ off,
                                             const int* __restrict__ csr,
                                             const float* __restrict__ a_src,
                                             const float* __restrict__ a_dst,
                                             const float* __restrict__ xp,
                                             void* out, const int* flags, int n) {
    int d = (blockIdx.x * 256 + threadIdx.x) >> 6;
    int lane = threadIdx.x & 63;
    if (d >= n) return;
    int h = lane >> 4;
    int beg = off[d], end = off[d + 1];
    float ad = a_dst[d * NHEADS + h];
    // pass 1: per-head max (self-loop included)
    float m = lrelu(a_src[d * NHEADS + h] + ad);
    for (int e = beg; e < end; ++e) {
        int s = csr[e];
        m = fmaxf(m, lrelu(a_src[s * NHEADS + h] + ad));
    }
    // pass 2: weighted accumulate; e == end is the self-loop
    float4 acc = {0.f, 0.f, 0.f, 0.f};
    float den = 0.f;
    for (int e = beg; e <= end; ++e) {
        int s = (e < end) ? csr[e] : d;
        float v = lrelu(a_src[s * NHEADS + h] + ad);
        float w = __expf(v - m);
        den += w;
        float4 xv = ((const float4*)(xp + (size_t)s * OUT_DIM))[lane];
        acc.x += w * xv.x; acc.y += w * xv.y; acc.z += w * xv.z; acc.w += w * xv.w;
    }
    float rd = 1.f / den;
    float o0 = fmaxf(acc.x * rd, 0.f);
    float o1 = fmaxf(acc.y * rd, 0.f);
    float o2 = fmaxf(acc.z * rd, 0.f);
    float o3 = fmaxf(acc.w * rd, 0.f);
    size_t idx = (size_t)d * OUT_DIM + lane * 4;
    if (flags[0]) {
        unsigned short p[4] = {f2bf(o0), f2bf(o1), f2bf(o2), f2bf(o3)};
        *(uint2*)((unsigned short*)out + idx) = *(const uint2*)p;
    } else {
        float p[4] = {o0, o1, o2, o3};
        *(float4*)((float*)out + idx) = *(const float4*)p;
    }
}

extern "C" void kernel_launch(void* const* d_in, const int* in_sizes, int n_in,
                              void* d_out, int out_size, void* d_ws, size_t ws_size,
                              hipStream_t stream) {
    const void* x    = d_in[0];
    const void* eidx = d_in[1];
    const void* W    = d_in[2];
    const void* as   = d_in[3];
    const void* ad   = d_in[4];
    int n = in_sizes[0] / IN_DIM;   // 50000
    int E = in_sizes[1] / 2;        // 800000

    char* ws = (char*)d_ws;
    size_t off_b = 0;
    auto alloc = [&](size_t bytes) -> void* {
        void* p = ws + off_b;
        off_b += (bytes + 255) & ~(size_t)255;
        return p;
    };
    int*   flags  = (int*)alloc(16);
    float* Wf     = (float*)alloc((size_t)IN_DIM * OUT_DIM * 4);
    float* asf    = (float*)alloc(256 * 4);
    float* adf    = (float*)alloc(256 * 4);
    float* xp     = (float*)alloc((size_t)n * OUT_DIM * 4);
    float* a_src  = (float*)alloc((size_t)n * NHEADS * 4);
    float* a_dst  = (float*)alloc((size_t)n * NHEADS * 4);
    int*   cnt    = (int*)alloc((size_t)n * 4);
    int*   offs   = (int*)alloc((size_t)(n + 1) * 4);
    int*   cursor = (int*)alloc((size_t)n * 4);
    int*   csr    = (int*)alloc((size_t)E * 4);

    hipMemsetAsync(cnt, 0, (size_t)n * 4, stream);

    hipLaunchKernelGGL(k_detect, dim3(1), dim3(64), 0, stream, x, eidx, flags);
    hipLaunchKernelGGL(k_convert, dim3((IN_DIM * OUT_DIM + 512 + 255) / 256), dim3(256), 0, stream,
                       W, as, ad, Wf, asf, adf, flags);
    hipLaunchKernelGGL(k_gemm, dim3((n + 15) / 16), dim3(256), 0, stream, x, Wf, xp, flags, n);
    hipLaunchKernelGGL(k_attdot, dim3((n + 3) / 4), dim3(256), 0, stream, xp, asf, adf, a_src, a_dst, n);
    hipLaunchKernelGGL(k_hist, dim3((E + 255) / 256), dim3(256), 0, stream, eidx, cnt, flags, E);
    hipLaunchKernelGGL(k_scan, dim3(1), dim3(256), 0, stream, cnt, offs, cursor, n);
    hipLaunchKernelGGL(k_scatter, dim3((E + 255) / 256), dim3(256), 0, stream, eidx, cursor, csr, flags, E);
    hipLaunchKernelGGL(k_agg, dim3((n + 3) / 4), dim3(256), 0, stream,
                       offs, csr, a_src, a_dst, xp, d_out, flags, n);
}

// Round 3
// 367.498 us; speedup vs baseline: 9.1532x; 2.0600x over previous
//
#include <hip/hip_runtime.h>
#include <hip/hip_bf16.h>

#define IN_DIM 256
#define OUT_DIM 256
#define NHEADS 4
#define NEG_SLOPE 0.2f

typedef unsigned short u16;
typedef __attribute__((ext_vector_type(8))) short short8;
typedef __attribute__((ext_vector_type(4))) float f32x4;

__device__ __forceinline__ float bf2f(u16 v) {
    return __uint_as_float(((unsigned int)v) << 16);
}
__device__ __forceinline__ u16 f2bf(float f) {
    unsigned int b = __float_as_uint(f);
    b += 0x7FFFu + ((b >> 16) & 1u);   // RNE
    return (u16)(b >> 16);
}
__device__ __forceinline__ float lrelu(float v) { return v > 0.f ? v : NEG_SLOPE * v; }

__device__ __forceinline__ void eread(const void* e, int is64, int i, int E, int& s, int& d) {
    if (is64) {
        const long long* p = (const long long*)e;
        s = (int)p[i]; d = (int)p[(size_t)E + i];
    } else {
        const int* p = (const int*)e;
        s = p[i]; d = p[(size_t)E + i];
    }
}

// ---------- dtype detection: flags[0]=x is bf16, flags[1]=edge_index is int64 ----------
__global__ void k_detect(const void* x, const void* eidx, int* flags) {
    int t = threadIdx.x;  // 64 threads
    const u16* u = (const u16*)x;
    u16 v = u[2 * t];
    int e = (v >> 7) & 0xFF;
    int sane = (e >= 118 && e <= 137) || ((v & 0x7FFFu) == 0);
    unsigned long long mf = __ballot(sane);
    const int* ip = (const int*)eidx;
    unsigned long long mi = __ballot(ip[2 * t + 1] == 0);
    if (t == 0) {
        flags[0] = (__popcll(mf) >= 48) ? 1 : 0;
        flags[1] = (mi == ~0ull) ? 1 : 0;
    }
}

// ---------- convert: Wt bf16 [n][k] (transposed), att vectors fp32 ----------
__global__ void k_convert(const void* W, const void* as, const void* ad,
                          u16* Wtb, float* asf, float* adf, const int* flags) {
    int i = blockIdx.x * 256 + threadIdx.x;
    int isb = flags[0];
    if (i < IN_DIM * OUT_DIM) {
        int nOut = i >> 8, k = i & 255;
        float w = isb ? bf2f(((const u16*)W)[(size_t)k * OUT_DIM + nOut])
                      : ((const float*)W)[(size_t)k * OUT_DIM + nOut];
        Wtb[i] = f2bf(w);   // exact round-trip if already bf16
    } else if (i < IN_DIM * OUT_DIM + 256) {
        int j = i - IN_DIM * OUT_DIM;
        asf[j] = isb ? bf2f(((const u16*)as)[j]) : ((const float*)as)[j];
    } else if (i < IN_DIM * OUT_DIM + 512) {
        int j = i - IN_DIM * OUT_DIM - 256;
        adf[j] = isb ? bf2f(((const u16*)ad)[j]) : ((const float*)ad)[j];
    }
}

// ---------- MFMA bf16 GEMM: xp = x @ W, fp32 accumulate ----------
// block 256 thr = 4 waves (2x2), block tile 128x128, wave tile 64x64 (4x4 of 16x16x32)
__global__ __launch_bounds__(256) void k_gemm(const void* __restrict__ x,
                                              const u16* __restrict__ Wtb,
                                              float* __restrict__ xp,
                                              const int* __restrict__ flags, int n) {
    __shared__ u16 As[128][32];   // [m][k] bf16, 8 KB
    __shared__ u16 Bs[128][32];   // [nOut][k] bf16, 8 KB
    const int t = threadIdx.x;
    const int row0 = blockIdx.x * 128;
    const int col0 = blockIdx.y * 128;
    const int wave = t >> 6, lane = t & 63;
    const int q = lane >> 4, l16 = lane & 15;
    const int wm = (wave >> 1) * 64, wn = (wave & 1) * 64;
    const int isb = flags[0];
    f32x4 acc[4][4];
#pragma unroll
    for (int a = 0; a < 4; ++a)
#pragma unroll
        for (int b = 0; b < 4; ++b) acc[a][b] = (f32x4){0.f, 0.f, 0.f, 0.f};

    const int sr = t >> 3;        // 0..31
    const int sk = (t & 7) * 4;   // 0,4,...,28

    for (int k0 = 0; k0 < IN_DIM; k0 += 32) {
#pragma unroll
        for (int i = 0; i < 4; ++i) {
            int rr = sr + i * 32;
            int grow = row0 + rr; if (grow >= n) grow = n - 1;   // clamp; stores guarded
            uint2 pk;
            if (isb) {
                pk = *(const uint2*)((const u16*)x + (size_t)grow * IN_DIM + k0 + sk);
            } else {
                const float* xf = (const float*)x + (size_t)grow * IN_DIM + k0 + sk;
                float4 v = *(const float4*)xf;
                pk.x = ((unsigned)f2bf(v.y) << 16) | f2bf(v.x);
                pk.y = ((unsigned)f2bf(v.w) << 16) | f2bf(v.z);
            }
            *(uint2*)&As[rr][sk] = pk;
            uint2 pb = *(const uint2*)(Wtb + (size_t)(col0 + rr) * IN_DIM + k0 + sk);
            *(uint2*)&Bs[rr][sk] = pb;
        }
        __syncthreads();
        short8 af[4], bfr[4];
#pragma unroll
        for (int mt = 0; mt < 4; ++mt)
            af[mt] = *(const short8*)&As[wm + mt * 16 + l16][q * 8];
#pragma unroll
        for (int nt = 0; nt < 4; ++nt)
            bfr[nt] = *(const short8*)&Bs[wn + nt * 16 + l16][q * 8];
#pragma unroll
        for (int mt = 0; mt < 4; ++mt)
#pragma unroll
            for (int nt = 0; nt < 4; ++nt)
                acc[mt][nt] = __builtin_amdgcn_mfma_f32_16x16x32_bf16(
                    af[mt], bfr[nt], acc[mt][nt], 0, 0, 0);
        __syncthreads();
    }
    // C/D layout: col = lane&15, row = quad*4 + reg
#pragma unroll
    for (int mt = 0; mt < 4; ++mt) {
#pragma unroll
        for (int nt = 0; nt < 4; ++nt) {
            int col = col0 + wn + nt * 16 + l16;
#pragma unroll
            for (int r = 0; r < 4; ++r) {
                int row = row0 + wm + mt * 16 + q * 4 + r;
                if (row < n) xp[(size_t)row * OUT_DIM + col] = acc[mt][nt][r];
            }
        }
    }
}

// ---------- a_src/a_dst: one wave per node ----------
__global__ __launch_bounds__(256) void k_attdot(const float* __restrict__ xp,
                                                const float* __restrict__ asf,
                                                const float* __restrict__ adf,
                                                float* a_src, float* a_dst, int n) {
    int wave = (blockIdx.x * 256 + threadIdx.x) >> 6;
    int lane = threadIdx.x & 63;
    if (wave >= n) return;
    float4 v = ((const float4*)(xp + (size_t)wave * OUT_DIM))[lane];
    float4 s4 = ((const float4*)asf)[lane];
    float4 d4 = ((const float4*)adf)[lane];
    float ps = v.x * s4.x + v.y * s4.y + v.z * s4.z + v.w * s4.w;
    float pd = v.x * d4.x + v.y * d4.y + v.z * d4.z + v.w * d4.w;
#pragma unroll
    for (int m = 1; m < 16; m <<= 1) { ps += __shfl_xor(ps, m); pd += __shfl_xor(pd, m); }
    if ((lane & 15) == 0) {
        int h = lane >> 4;
        a_src[wave * NHEADS + h] = ps;
        a_dst[wave * NHEADS + h] = pd;
    }
}

// ---------- CSR build: in-degree histogram ----------
__global__ __launch_bounds__(256) void k_hist(const void* eidx, int* cnt,
                                              const int* flags, int E) {
    int i = blockIdx.x * 256 + threadIdx.x;
    if (i >= E) return;
    int s, d;
    eread(eidx, flags[1], i, E, s, d);
    atomicAdd(&cnt[d], 1);
}

// ---------- hierarchical scan: per-block sums ----------
__global__ __launch_bounds__(256) void k_scan1(const int* __restrict__ cnt, int* part, int n) {
    int i = blockIdx.x * 256 + threadIdx.x;
    int v = (i < n) ? cnt[i] : 0;
#pragma unroll
    for (int s = 1; s < 64; s <<= 1) v += __shfl_xor(v, s);
    __shared__ int wsum[4];
    if ((threadIdx.x & 63) == 0) wsum[threadIdx.x >> 6] = v;
    __syncthreads();
    if (threadIdx.x == 0) part[blockIdx.x] = wsum[0] + wsum[1] + wsum[2] + wsum[3];
}

// ---------- scan block sums (nb <= 256), write total to off[n] ----------
__global__ void k_scan2(const int* __restrict__ part, int* partx, int* off, int nb, int n) {
    __shared__ int tmp[256];
    int t = threadIdx.x;
    int v = (t < nb) ? part[t] : 0;
    tmp[t] = v; __syncthreads();
    for (int s = 1; s < 256; s <<= 1) {
        int u = (t >= s) ? tmp[t - s] : 0;
        __syncthreads();
        tmp[t] += u;
        __syncthreads();
    }
    if (t < nb) partx[t] = tmp[t] - v;
    if (t == 255) off[n] = tmp[255];
}

// ---------- local scan + base -> off, cursor ----------
__global__ __launch_bounds__(256) void k_scan3(const int* __restrict__ cnt,
                                               const int* __restrict__ partx,
                                               int* off, int* cursor, int n) {
    __shared__ int tmp[256];
    int t = threadIdx.x;
    int i = blockIdx.x * 256 + t;
    int v = (i < n) ? cnt[i] : 0;
    tmp[t] = v; __syncthreads();
    for (int s = 1; s < 256; s <<= 1) {
        int u = (t >= s) ? tmp[t - s] : 0;
        __syncthreads();
        tmp[t] += u;
        __syncthreads();
    }
    if (i < n) {
        int ex = partx[blockIdx.x] + tmp[t] - v;
        off[i] = ex; cursor[i] = ex;
    }
}

// ---------- scatter src indices into CSR buckets ----------
__global__ __launch_bounds__(256) void k_scatter(const void* eidx, int* cursor, int* csr,
                                                 const int* flags, int E) {
    int i = blockIdx.x * 256 + threadIdx.x;
    if (i >= E) return;
    int s, d;
    eread(eidx, flags[1], i, E, s, d);
    int pos = atomicAdd(&cursor[d], 1);
    csr[pos] = s;
}

// ---------- wave-per-dst single-pass online-softmax gather, relu, store ----------
__global__ __launch_bounds__(256) void k_agg(const int* __restrict__ off,
                                             const int* __restrict__ csr,
                                             const float* __restrict__ a_src,
                                             const float* __restrict__ a_dst,
                                             const float* __restrict__ xp,
                                             void* out, const int* flags, int n) {
    int d = (blockIdx.x * 256 + threadIdx.x) >> 6;
    int lane = threadIdx.x & 63;
    if (d >= n) return;
    int h = lane >> 4;
    int beg = off[d], end = off[d + 1];
    float ad = a_dst[d * NHEADS + h];
    // init with the self-loop (w = 1 at m = its own logit)
    float m = lrelu(a_src[d * NHEADS + h] + ad);
    float4 acc = ((const float4*)(xp + (size_t)d * OUT_DIM))[lane];
    float den = 1.f;
    for (int e = beg; e < end; ++e) {
        int s = csr[e];
        float v = lrelu(a_src[s * NHEADS + h] + ad);
        float mn = fmaxf(m, v);
        float c = __expf(m - mn);    // 1.0 when max unchanged
        float w = __expf(v - mn);
        float4 xv = ((const float4*)(xp + (size_t)s * OUT_DIM))[lane];
        acc.x = acc.x * c + w * xv.x;
        acc.y = acc.y * c + w * xv.y;
        acc.z = acc.z * c + w * xv.z;
        acc.w = acc.w * c + w * xv.w;
        den = den * c + w;
        m = mn;
    }
    float rd = 1.f / den;
    float o0 = fmaxf(acc.x * rd, 0.f);
    float o1 = fmaxf(acc.y * rd, 0.f);
    float o2 = fmaxf(acc.z * rd, 0.f);
    float o3 = fmaxf(acc.w * rd, 0.f);
    size_t idx = (size_t)d * OUT_DIM + lane * 4;
    if (flags[0]) {
        u16 p[4] = {f2bf(o0), f2bf(o1), f2bf(o2), f2bf(o3)};
        *(uint2*)((u16*)out + idx) = *(const uint2*)p;
    } else {
        float p[4] = {o0, o1, o2, o3};
        *(float4*)((float*)out + idx) = *(const float4*)p;
    }
}

extern "C" void kernel_launch(void* const* d_in, const int* in_sizes, int n_in,
                              void* d_out, int out_size, void* d_ws, size_t ws_size,
                              hipStream_t stream) {
    const void* x    = d_in[0];
    const void* eidx = d_in[1];
    const void* W    = d_in[2];
    const void* as   = d_in[3];
    const void* ad   = d_in[4];
    int n = in_sizes[0] / IN_DIM;   // 50000
    int E = in_sizes[1] / 2;        // 800000

    char* ws = (char*)d_ws;
    size_t off_b = 0;
    auto alloc = [&](size_t bytes) -> void* {
        void* p = ws + off_b;
        off_b += (bytes + 255) & ~(size_t)255;
        return p;
    };
    int*   flags  = (int*)alloc(16);
    u16*   Wtb    = (u16*)alloc((size_t)IN_DIM * OUT_DIM * 2);
    float* asf    = (float*)alloc(256 * 4);
    float* adf    = (float*)alloc(256 * 4);
    float* xp     = (float*)alloc((size_t)n * OUT_DIM * 4);
    float* a_src  = (float*)alloc((size_t)n * NHEADS * 4);
    float* a_dst  = (float*)alloc((size_t)n * NHEADS * 4);
    int*   cnt    = (int*)alloc((size_t)n * 4);
    int*   offs   = (int*)alloc((size_t)(n + 1) * 4);
    int*   cursor = (int*)alloc((size_t)n * 4);
    int*   csr    = (int*)alloc((size_t)E * 4);
    int*   part   = (int*)alloc(256 * 4);
    int*   partx  = (int*)alloc(256 * 4);

    int nb = (n + 255) / 256;   // 196 blocks for the scan hierarchy

    hipMemsetAsync(cnt, 0, (size_t)n * 4, stream);

    hipLaunchKernelGGL(k_detect, dim3(1), dim3(64), 0, stream, x, eidx, flags);
    hipLaunchKernelGGL(k_convert, dim3((IN_DIM * OUT_DIM + 512 + 255) / 256), dim3(256), 0, stream,
                       W, as, ad, Wtb, asf, adf, flags);
    hipLaunchKernelGGL(k_gemm, dim3((n + 127) / 128, OUT_DIM / 128), dim3(256), 0, stream,
                       x, Wtb, xp, flags, n);
    hipLaunchKernelGGL(k_attdot, dim3((n + 3) / 4), dim3(256), 0, stream, xp, asf, adf, a_src, a_dst, n);
    hipLaunchKernelGGL(k_hist, dim3((E + 255) / 256), dim3(256), 0, stream, eidx, cnt, flags, E);
    hipLaunchKernelGGL(k_scan1, dim3(nb), dim3(256), 0, stream, cnt, part, n);
    hipLaunchKernelGGL(k_scan2, dim3(1), dim3(256), 0, stream, part, partx, offs, nb, n);
    hipLaunchKernelGGL(k_scan3, dim3(nb), dim3(256), 0, stream, cnt, partx, offs, cursor, n);
    hipLaunchKernelGGL(k_scatter, dim3((E + 255) / 256), dim3(256), 0, stream, eidx, cursor, csr, flags, E);
    hipLaunchKernelGGL(k_agg, dim3((n + 3) / 4), dim3(256), 0, stream,
                       offs, csr, a_src, a_dst, xp, d_out, flags, n);
}

// Round 4
// 312.270 us; speedup vs baseline: 10.7720x; 1.1769x over previous
//
#include <hip/hip_runtime.h>
#include <hip/hip_bf16.h>

#define IN_DIM 256
#define OUT_DIM 256
#define NHEADS 4
#define NEG_SLOPE 0.2f

typedef unsigned short u16;
typedef __attribute__((ext_vector_type(8))) short short8;
typedef __attribute__((ext_vector_type(4))) float f32x4;

__device__ __forceinline__ float bf2f(u16 v) {
    return __uint_as_float(((unsigned int)v) << 16);
}
__device__ __forceinline__ u16 f2bf(float f) {
    unsigned int b = __float_as_uint(f);
    b += 0x7FFFu + ((b >> 16) & 1u);   // RNE
    return (u16)(b >> 16);
}
// unpack 4 consecutive bf16 (uint2) -> float4
__device__ __forceinline__ float4 bf4(uint2 p) {
    float4 r;
    r.x = __uint_as_float(p.x << 16);
    r.y = __uint_as_float(p.x & 0xFFFF0000u);
    r.z = __uint_as_float(p.y << 16);
    r.w = __uint_as_float(p.y & 0xFFFF0000u);
    return r;
}
__device__ __forceinline__ float lrelu(float v) { return v > 0.f ? v : NEG_SLOPE * v; }

__device__ __forceinline__ void eread(const void* e, int is64, int i, int E, int& s, int& d) {
    if (is64) {
        const long long* p = (const long long*)e;
        s = (int)p[i]; d = (int)p[(size_t)E + i];
    } else {
        const int* p = (const int*)e;
        s = p[i]; d = p[(size_t)E + i];
    }
}

// ---------- dtype detection: flags[0]=x is bf16, flags[1]=edge_index is int64 ----------
__global__ void k_detect(const void* x, const void* eidx, int* flags) {
    int t = threadIdx.x;  // 64 threads
    const u16* u = (const u16*)x;
    u16 v = u[2 * t];
    int e = (v >> 7) & 0xFF;
    int sane = (e >= 118 && e <= 137) || ((v & 0x7FFFu) == 0);
    unsigned long long mf = __ballot(sane);
    const int* ip = (const int*)eidx;
    unsigned long long mi = __ballot(ip[2 * t + 1] == 0);
    if (t == 0) {
        flags[0] = (__popcll(mf) >= 48) ? 1 : 0;
        flags[1] = (mi == ~0ull) ? 1 : 0;
    }
}

// ---------- convert: Wt bf16 [n][k] (transposed), att vectors fp32 ----------
__global__ void k_convert(const void* W, const void* as, const void* ad,
                          u16* Wtb, float* asf, float* adf, const int* flags) {
    int i = blockIdx.x * 256 + threadIdx.x;
    int isb = flags[0];
    if (i < IN_DIM * OUT_DIM) {
        int nOut = i >> 8, k = i & 255;
        float w = isb ? bf2f(((const u16*)W)[(size_t)k * OUT_DIM + nOut])
                      : ((const float*)W)[(size_t)k * OUT_DIM + nOut];
        Wtb[i] = f2bf(w);   // exact round-trip if already bf16
    } else if (i < IN_DIM * OUT_DIM + 256) {
        int j = i - IN_DIM * OUT_DIM;
        asf[j] = isb ? bf2f(((const u16*)as)[j]) : ((const float*)as)[j];
    } else if (i < IN_DIM * OUT_DIM + 512) {
        int j = i - IN_DIM * OUT_DIM - 256;
        adf[j] = isb ? bf2f(((const u16*)ad)[j]) : ((const float*)ad)[j];
    }
}

// ---------- MFMA bf16 GEMM: xp = x @ W (bf16 out, fp32 accumulate) ----------
// block 256 thr = 4 waves (2x2), block tile 128x128, wave tile 64x64 (4x4 of 16x16x32)
__global__ __launch_bounds__(256) void k_gemm(const void* __restrict__ x,
                                              const u16* __restrict__ Wtb,
                                              u16* __restrict__ xpb,
                                              const int* __restrict__ flags, int n) {
    __shared__ u16 As[128][32];   // [m][k] bf16, 8 KB
    __shared__ u16 Bs[128][32];   // [nOut][k] bf16, 8 KB
    const int t = threadIdx.x;
    const int row0 = blockIdx.x * 128;
    const int col0 = blockIdx.y * 128;
    const int wave = t >> 6, lane = t & 63;
    const int q = lane >> 4, l16 = lane & 15;
    const int wm = (wave >> 1) * 64, wn = (wave & 1) * 64;
    const int isb = flags[0];
    f32x4 acc[4][4];
#pragma unroll
    for (int a = 0; a < 4; ++a)
#pragma unroll
        for (int b = 0; b < 4; ++b) acc[a][b] = (f32x4){0.f, 0.f, 0.f, 0.f};

    const int sr = t >> 3;        // 0..31
    const int sk = (t & 7) * 4;   // 0,4,...,28

    for (int k0 = 0; k0 < IN_DIM; k0 += 32) {
#pragma unroll
        for (int i = 0; i < 4; ++i) {
            int rr = sr + i * 32;
            int grow = row0 + rr; if (grow >= n) grow = n - 1;   // clamp; stores guarded
            uint2 pk;
            if (isb) {
                pk = *(const uint2*)((const u16*)x + (size_t)grow * IN_DIM + k0 + sk);
            } else {
                const float* xf = (const float*)x + (size_t)grow * IN_DIM + k0 + sk;
                float4 v = *(const float4*)xf;
                pk.x = ((unsigned)f2bf(v.y) << 16) | f2bf(v.x);
                pk.y = ((unsigned)f2bf(v.w) << 16) | f2bf(v.z);
            }
            *(uint2*)&As[rr][sk] = pk;
            uint2 pb = *(const uint2*)(Wtb + (size_t)(col0 + rr) * IN_DIM + k0 + sk);
            *(uint2*)&Bs[rr][sk] = pb;
        }
        __syncthreads();
        short8 af[4], bfr[4];
#pragma unroll
        for (int mt = 0; mt < 4; ++mt)
            af[mt] = *(const short8*)&As[wm + mt * 16 + l16][q * 8];
#pragma unroll
        for (int nt = 0; nt < 4; ++nt)
            bfr[nt] = *(const short8*)&Bs[wn + nt * 16 + l16][q * 8];
#pragma unroll
        for (int mt = 0; mt < 4; ++mt)
#pragma unroll
            for (int nt = 0; nt < 4; ++nt)
                acc[mt][nt] = __builtin_amdgcn_mfma_f32_16x16x32_bf16(
                    af[mt], bfr[nt], acc[mt][nt], 0, 0, 0);
        __syncthreads();
    }
    // C/D layout: col = lane&15, row = quad*4 + reg ; store bf16
#pragma unroll
    for (int mt = 0; mt < 4; ++mt) {
#pragma unroll
        for (int nt = 0; nt < 4; ++nt) {
            int col = col0 + wn + nt * 16 + l16;
#pragma unroll
            for (int r = 0; r < 4; ++r) {
                int row = row0 + wm + mt * 16 + q * 4 + r;
                if (row < n) xpb[(size_t)row * OUT_DIM + col] = f2bf(acc[mt][nt][r]);
            }
        }
    }
}

// ---------- a_src/a_dst: one wave per node (bf16 xp) ----------
__global__ __launch_bounds__(256) void k_attdot(const u16* __restrict__ xpb,
                                                const float* __restrict__ asf,
                                                const float* __restrict__ adf,
                                                float* a_src, float* a_dst, int n) {
    int wave = (blockIdx.x * 256 + threadIdx.x) >> 6;
    int lane = threadIdx.x & 63;
    if (wave >= n) return;
    float4 v = bf4(((const uint2*)(xpb + (size_t)wave * OUT_DIM))[lane]);
    float4 s4 = ((const float4*)asf)[lane];
    float4 d4 = ((const float4*)adf)[lane];
    float ps = v.x * s4.x + v.y * s4.y + v.z * s4.z + v.w * s4.w;
    float pd = v.x * d4.x + v.y * d4.y + v.z * d4.z + v.w * d4.w;
#pragma unroll
    for (int m = 1; m < 16; m <<= 1) { ps += __shfl_xor(ps, m); pd += __shfl_xor(pd, m); }
    if ((lane & 15) == 0) {
        int h = lane >> 4;
        a_src[wave * NHEADS + h] = ps;
        a_dst[wave * NHEADS + h] = pd;
    }
}

// ---------- CSR build: in-degree histogram ----------
__global__ __launch_bounds__(256) void k_hist(const void* eidx, int* cnt,
                                              const int* flags, int E) {
    int i = blockIdx.x * 256 + threadIdx.x;
    if (i >= E) return;
    int s, d;
    eread(eidx, flags[1], i, E, s, d);
    atomicAdd(&cnt[d], 1);
}

// ---------- hierarchical scan: per-block sums ----------
__global__ __launch_bounds__(256) void k_scan1(const int* __restrict__ cnt, int* part, int n) {
    int i = blockIdx.x * 256 + threadIdx.x;
    int v = (i < n) ? cnt[i] : 0;
#pragma unroll
    for (int s = 1; s < 64; s <<= 1) v += __shfl_xor(v, s);
    __shared__ int wsum[4];
    if ((threadIdx.x & 63) == 0) wsum[threadIdx.x >> 6] = v;
    __syncthreads();
    if (threadIdx.x == 0) part[blockIdx.x] = wsum[0] + wsum[1] + wsum[2] + wsum[3];
}

// ---------- scan block sums (nb <= 256), write total to off[n] ----------
__global__ void k_scan2(const int* __restrict__ part, int* partx, int* off, int nb, int n) {
    __shared__ int tmp[256];
    int t = threadIdx.x;
    int v = (t < nb) ? part[t] : 0;
    tmp[t] = v; __syncthreads();
    for (int s = 1; s < 256; s <<= 1) {
        int u = (t >= s) ? tmp[t - s] : 0;
        __syncthreads();
        tmp[t] += u;
        __syncthreads();
    }
    if (t < nb) partx[t] = tmp[t] - v;
    if (t == 255) off[n] = tmp[255];
}

// ---------- local scan + base -> off, cursor ----------
__global__ __launch_bounds__(256) void k_scan3(const int* __restrict__ cnt,
                                               const int* __restrict__ partx,
                                               int* off, int* cursor, int n) {
    __shared__ int tmp[256];
    int t = threadIdx.x;
    int i = blockIdx.x * 256 + t;
    int v = (i < n) ? cnt[i] : 0;
    tmp[t] = v; __syncthreads();
    for (int s = 1; s < 256; s <<= 1) {
        int u = (t >= s) ? tmp[t - s] : 0;
        __syncthreads();
        tmp[t] += u;
        __syncthreads();
    }
    if (i < n) {
        int ex = partx[blockIdx.x] + tmp[t] - v;
        off[i] = ex; cursor[i] = ex;
    }
}

// ---------- scatter src indices into CSR buckets ----------
__global__ __launch_bounds__(256) void k_scatter(const void* eidx, int* cursor, int* csr,
                                                 const int* flags, int E) {
    int i = blockIdx.x * 256 + threadIdx.x;
    if (i >= E) return;
    int s, d;
    eread(eidx, flags[1], i, E, s, d);
    int pos = atomicAdd(&cursor[d], 1);
    csr[pos] = s;
}

// ---------- wave-per-dst single-pass online-softmax gather (bf16 xp), relu, store ----------
__global__ __launch_bounds__(256) void k_agg(const int* __restrict__ off,
                                             const int* __restrict__ csr,
                                             const float* __restrict__ a_src,
                                             const float* __restrict__ a_dst,
                                             const u16* __restrict__ xpb,
                                             void* out, const int* flags, int n) {
    int d = (blockIdx.x * 256 + threadIdx.x) >> 6;
    int lane = threadIdx.x & 63;
    if (d >= n) return;
    int h = lane >> 4;
    int beg = off[d], end = off[d + 1];
    float ad = a_dst[d * NHEADS + h];
    // init with the self-loop (w = 1 at m = its own logit)
    float m = lrelu(a_src[d * NHEADS + h] + ad);
    float4 acc = bf4(((const uint2*)(xpb + (size_t)d * OUT_DIM))[lane]);
    float den = 1.f;
    int e = beg;
    // 4-edge unroll: 4 independent row-gathers in flight per exp-rescale step
    for (; e + 4 <= end; e += 4) {
        int s0 = csr[e], s1 = csr[e + 1], s2 = csr[e + 2], s3 = csr[e + 3];
        float v0 = lrelu(a_src[s0 * NHEADS + h] + ad);
        float v1 = lrelu(a_src[s1 * NHEADS + h] + ad);
        float v2 = lrelu(a_src[s2 * NHEADS + h] + ad);
        float v3 = lrelu(a_src[s3 * NHEADS + h] + ad);
        uint2 p0 = ((const uint2*)(xpb + (size_t)s0 * OUT_DIM))[lane];
        uint2 p1 = ((const uint2*)(xpb + (size_t)s1 * OUT_DIM))[lane];
        uint2 p2 = ((const uint2*)(xpb + (size_t)s2 * OUT_DIM))[lane];
        uint2 p3 = ((const uint2*)(xpb + (size_t)s3 * OUT_DIM))[lane];
        float mn = fmaxf(fmaxf(m, fmaxf(v0, v1)), fmaxf(v2, v3));
        float c  = __expf(m - mn);
        float w0 = __expf(v0 - mn), w1 = __expf(v1 - mn);
        float w2 = __expf(v2 - mn), w3 = __expf(v3 - mn);
        float4 x0 = bf4(p0), x1 = bf4(p1), x2 = bf4(p2), x3 = bf4(p3);
        acc.x = acc.x * c + w0 * x0.x + w1 * x1.x + w2 * x2.x + w3 * x3.x;
        acc.y = acc.y * c + w0 * x0.y + w1 * x1.y + w2 * x2.y + w3 * x3.y;
        acc.z = acc.z * c + w0 * x0.z + w1 * x1.z + w2 * x2.z + w3 * x3.z;
        acc.w = acc.w * c + w0 * x0.w + w1 * x1.w + w2 * x2.w + w3 * x3.w;
        den = den * c + w0 + w1 + w2 + w3;
        m = mn;
    }
    for (; e < end; ++e) {
        int s = csr[e];
        float v = lrelu(a_src[s * NHEADS + h] + ad);
        float mn = fmaxf(m, v);
        float c = __expf(m - mn);
        float w = __expf(v - mn);
        float4 xv = bf4(((const uint2*)(xpb + (size_t)s * OUT_DIM))[lane]);
        acc.x = acc.x * c + w * xv.x;
        acc.y = acc.y * c + w * xv.y;
        acc.z = acc.z * c + w * xv.z;
        acc.w = acc.w * c + w * xv.w;
        den = den * c + w;
        m = mn;
    }
    float rd = 1.f / den;
    float o0 = fmaxf(acc.x * rd, 0.f);
    float o1 = fmaxf(acc.y * rd, 0.f);
    float o2 = fmaxf(acc.z * rd, 0.f);
    float o3 = fmaxf(acc.w * rd, 0.f);
    size_t idx = (size_t)d * OUT_DIM + lane * 4;
    if (flags[0]) {
        u16 p[4] = {f2bf(o0), f2bf(o1), f2bf(o2), f2bf(o3)};
        *(uint2*)((u16*)out + idx) = *(const uint2*)p;
    } else {
        float p[4] = {o0, o1, o2, o3};
        *(float4*)((float*)out + idx) = *(const float4*)p;
    }
}

extern "C" void kernel_launch(void* const* d_in, const int* in_sizes, int n_in,
                              void* d_out, int out_size, void* d_ws, size_t ws_size,
                              hipStream_t stream) {
    const void* x    = d_in[0];
    const void* eidx = d_in[1];
    const void* W    = d_in[2];
    const void* as   = d_in[3];
    const void* ad   = d_in[4];
    int n = in_sizes[0] / IN_DIM;   // 50000
    int E = in_sizes[1] / 2;        // 800000

    char* ws = (char*)d_ws;
    size_t off_b = 0;
    auto alloc = [&](size_t bytes) -> void* {
        void* p = ws + off_b;
        off_b += (bytes + 255) & ~(size_t)255;
        return p;
    };
    int*   flags  = (int*)alloc(16);
    u16*   Wtb    = (u16*)alloc((size_t)IN_DIM * OUT_DIM * 2);
    float* asf    = (float*)alloc(256 * 4);
    float* adf    = (float*)alloc(256 * 4);
    u16*   xpb    = (u16*)alloc((size_t)n * OUT_DIM * 2);
    float* a_src  = (float*)alloc((size_t)n * NHEADS * 4);
    float* a_dst  = (float*)alloc((size_t)n * NHEADS * 4);
    int*   cnt    = (int*)alloc((size_t)n * 4);
    int*   offs   = (int*)alloc((size_t)(n + 1) * 4);
    int*   cursor = (int*)alloc((size_t)n * 4);
    int*   csr    = (int*)alloc((size_t)E * 4);
    int*   part   = (int*)alloc(256 * 4);
    int*   partx  = (int*)alloc(256 * 4);

    int nb = (n + 255) / 256;   // scan hierarchy blocks (196 <= 256)

    hipMemsetAsync(cnt, 0, (size_t)n * 4, stream);

    hipLaunchKernelGGL(k_detect, dim3(1), dim3(64), 0, stream, x, eidx, flags);
    hipLaunchKernelGGL(k_convert, dim3((IN_DIM * OUT_DIM + 512 + 255) / 256), dim3(256), 0, stream,
                       W, as, ad, Wtb, asf, adf, flags);
    hipLaunchKernelGGL(k_gemm, dim3((n + 127) / 128, OUT_DIM / 128), dim3(256), 0, stream,
                       x, Wtb, xpb, flags, n);
    hipLaunchKernelGGL(k_attdot, dim3((n + 3) / 4), dim3(256), 0, stream, xpb, asf, adf, a_src, a_dst, n);
    hipLaunchKernelGGL(k_hist, dim3((E + 255) / 256), dim3(256), 0, stream, eidx, cnt, flags, E);
    hipLaunchKernelGGL(k_scan1, dim3(nb), dim3(256), 0, stream, cnt, part, n);
    hipLaunchKernelGGL(k_scan2, dim3(1), dim3(256), 0, stream, part, partx, offs, nb, n);
    hipLaunchKernelGGL(k_scan3, dim3(nb), dim3(256), 0, stream, cnt, partx, offs, cursor, n);
    hipLaunchKernelGGL(k_scatter, dim3((E + 255) / 256), dim3(256), 0, stream, eidx, cursor, csr, flags, E);
    hipLaunchKernelGGL(k_agg, dim3((n + 3) / 4), dim3(256), 0, stream,
                       offs, csr, a_src, a_dst, xpb, d_out, flags, n);
}